// Round 7
// baseline (65.176 us; speedup 1.0000x reference)
//
#include <hip/hip_runtime.h>
#include <hip/hip_bf16.h>

#define N_PTS 4096
#define D_EMB 64
#define TILE  128
#define NWAVE ((N_PTS / TILE) * (N_PTS / TILE) * 4)   // 4096 waves in main grid

typedef __attribute__((ext_vector_type(8))) short bf16x8;  // 8 bf16 = 4 VGPR
typedef __attribute__((ext_vector_type(4))) float f32x4;   // MFMA 16x16 acc

// ---------------------------------------------------------------------------
// Fused prep: bf16 hi/lo split + exact f32 row squared-norms.
// One wave per row; one pass over mapping.
// ---------------------------------------------------------------------------
__global__ void prep_kernel(const float* __restrict__ mapping,
                            ushort* __restrict__ Mhi,
                            ushort* __restrict__ Mlo,
                            float* __restrict__ nrm) {
  const int row = blockIdx.x;
  const int l = threadIdx.x;          // 0..63
  const int idx = row * D_EMB + l;
  const float x = mapping[idx];
  __hip_bfloat16 h = __float2bfloat16(x);
  const float hf = __bfloat162float(h);
  __hip_bfloat16 lo = __float2bfloat16(x - hf);
  Mhi[idx] = *reinterpret_cast<ushort*>(&h);
  Mlo[idx] = *reinterpret_cast<ushort*>(&lo);
  float s = x * x;
  #pragma unroll
  for (int off = 32; off > 0; off >>= 1) s += __shfl_down(s, off);
  if (l == 0) nrm[row] = s;
}

// ---------------------------------------------------------------------------
// MFMA gram + fused distortion partial sums.
// dot = hi.hi + lo.hi + hi.lo  (lo.lo dropped: rel err ~2^-18; norms exact,
// diagonal exact -> passed absmax 0.0 in R6).
//
// 256 thr = 4 waves (2x2), 128x128 tile/block, 64x64 per wave as 4x4 MFMA
// tiles of 16x16, K=64 = 2 steps of 32. Fragments load directly from global
// (panels are L1/L2-resident; no LDS, no barriers).
//   A: lane l -> row l&15,  k = (l>>4)*8 + j
//   B: lane l -> col l&15,  same addressing (B = M^T of row-major M)
//   C/D: col = lane&15, row = (lane>>4)*4 + reg   [verified m89 layout]
//
// R6 lesson: loading aH/aL/bH/bL up-front = 64 frag VGPRs live on top of
// 64 acc -> ~150+ VGPR -> 2-3 waves/SIMD -> the 64 scalar D-loads/lane in
// the epilogue had no latency cover (~30us observed vs ~12 model).
// Fix: PHASE the three products so <=3 fragment sets are live:
//   hi.hi (aH,bH) -> lo.hi (aL,bH; aL dies) -> hi.lo (aH,bL).
// Peak ~125 VGPR -> 4 waves/SIMD.
// R5 lesson kept: contention-free per-wave partial writes (NO atomics).
// R2/R3 lesson kept: no min-waves launch_bounds arg (forced spills).
// ---------------------------------------------------------------------------
__global__ __launch_bounds__(256) void distortion_main(
    const ushort* __restrict__ Mhi, const ushort* __restrict__ Mlo,
    const float* __restrict__ Dm, const float* __restrict__ nrm,
    double* __restrict__ part) {
  const int t = threadIdx.x;
  const int w = t >> 6, l = t & 63;
  const int r16 = l & 15;        // row/col within 16x16 fragment
  const int kg = l >> 4;         // k-group 0..3
  const int wr = w >> 1, wc = w & 1;
  const int i0 = blockIdx.y * TILE + wr * 64;   // wave row base
  const int j0 = blockIdx.x * TILE + wc * 64;   // wave col base

  f32x4 acc[4][4] = {};          // acc[m][n]: output rows m*16+, cols n*16+

  #pragma unroll
  for (int ks = 0; ks < 2; ++ks) {
    const int koff = ks * 32 + kg * 8;
    // ---- phase 1: hi.hi (aH, bH live)
    bf16x8 aH[4], bH[4];
    #pragma unroll
    for (int m = 0; m < 4; ++m)
      aH[m] = *(const bf16x8*)(Mhi + (size_t)(i0 + m * 16 + r16) * D_EMB + koff);
    #pragma unroll
    for (int n = 0; n < 4; ++n)
      bH[n] = *(const bf16x8*)(Mhi + (size_t)(j0 + n * 16 + r16) * D_EMB + koff);
    #pragma unroll
    for (int m = 0; m < 4; ++m)
      #pragma unroll
      for (int n = 0; n < 4; ++n)
        acc[m][n] = __builtin_amdgcn_mfma_f32_16x16x32_bf16(
            aH[m], bH[n], acc[m][n], 0, 0, 0);
    // ---- phase 2: lo.hi (aL joins, dies after; bH dies after)
    {
      bf16x8 aL[4];
      #pragma unroll
      for (int m = 0; m < 4; ++m)
        aL[m] = *(const bf16x8*)(Mlo + (size_t)(i0 + m * 16 + r16) * D_EMB + koff);
      #pragma unroll
      for (int m = 0; m < 4; ++m)
        #pragma unroll
        for (int n = 0; n < 4; ++n)
          acc[m][n] = __builtin_amdgcn_mfma_f32_16x16x32_bf16(
              aL[m], bH[n], acc[m][n], 0, 0, 0);
    }
    // ---- phase 3: hi.lo (bL replaces aL/bH)
    {
      bf16x8 bL[4];
      #pragma unroll
      for (int n = 0; n < 4; ++n)
        bL[n] = *(const bf16x8*)(Mlo + (size_t)(j0 + n * 16 + r16) * D_EMB + koff);
      #pragma unroll
      for (int m = 0; m < 4; ++m)
        #pragma unroll
        for (int n = 0; n < 4; ++n)
          acc[m][n] = __builtin_amdgcn_mfma_f32_16x16x32_bf16(
              aH[m], bL[n], acc[m][n], 0, 0, 0);
    }
  }

  // ---- epilogue: distances + distortion partial sums (all static indices)
  float rB[4];
  #pragma unroll
  for (int n = 0; n < 4; ++n) rB[n] = nrm[j0 + n * 16 + r16];

  float s1 = 0.f, s2 = 0.f, s3 = 0.f, s4 = 0.f;
  #pragma unroll
  for (int m = 0; m < 4; ++m) {
    #pragma unroll
    for (int reg = 0; reg < 4; ++reg) {
      const int gr = i0 + m * 16 + kg * 4 + reg;   // C/D row for this reg
      const float rA = nrm[gr];
      const float* __restrict__ Drow = Dm + (size_t)gr * N_PTS;
      #pragma unroll
      for (int n = 0; n < 4; ++n) {
        const int gc = j0 + n * 16 + r16;          // C/D col
        const float Dv = Drow[gc];
        const float dot = acc[m][n][reg];
        const float sq = fmaxf(rA + rB[n] - 2.f * dot, 0.f);
        float dd = __builtin_amdgcn_sqrtf(sq);
        const bool diag = (gr == gc);
        if (diag) dd = 0.f;                        // exact: ||x-x|| = 0
        const float denom = Dv + (diag ? 1.f : 0.f) + 1e-8f;
        const float rd = __builtin_amdgcn_rcpf(denom);
        const float av = dd * rd;                  // a = d/denom
        const float bv = Dv * rd;                  // b = D/denom
        s1 += av;
        s2 = fmaf(av, av, s2);
        s3 = fmaf(av, bv, s3);
        s4 = fmaf(bv, bv, s4);
      }
    }
  }

  // ---- wave shuffle reduce, one contention-free f64 write per wave
  #pragma unroll
  for (int off = 32; off > 0; off >>= 1) {
    s1 += __shfl_down(s1, off);
    s2 += __shfl_down(s2, off);
    s3 += __shfl_down(s3, off);
    s4 += __shfl_down(s4, off);
  }
  if (l == 0) {
    const int gw = ((blockIdx.y * gridDim.x + blockIdx.x) << 2) + w;
    part[0 * NWAVE + gw] = (double)s1;
    part[1 * NWAVE + gw] = (double)s2;
    part[2 * NWAVE + gw] = (double)s3;
    part[3 * NWAVE + gw] = (double)s4;
  }
}

// ---------------------------------------------------------------------------
// Reduce 4 x NWAVE partials; emit sum(dist) = s^2*S2 - 2 s S3 + S4, s=S1/S2.
// ---------------------------------------------------------------------------
__global__ __launch_bounds__(1024) void distortion_final(
    const double* __restrict__ part, float* __restrict__ out) {
  __shared__ double red[16][4];
  const int t = threadIdx.x;
  double s[4];
  #pragma unroll
  for (int k = 0; k < 4; ++k) {
    double v = 0.0;
    #pragma unroll
    for (int c = 0; c < NWAVE / 1024; ++c) v += part[k * NWAVE + c * 1024 + t];
    s[k] = v;
  }
  #pragma unroll
  for (int off = 32; off > 0; off >>= 1)
    #pragma unroll
    for (int k = 0; k < 4; ++k) s[k] += __shfl_down(s[k], off);
  const int w = t >> 6, l = t & 63;
  if (l == 0) {
    #pragma unroll
    for (int k = 0; k < 4; ++k) red[w][k] = s[k];
  }
  __syncthreads();
  if (t == 0) {
    double S0 = 0, S1 = 0, S2 = 0, S3 = 0;
    #pragma unroll
    for (int ww = 0; ww < 16; ++ww) {
      S0 += red[ww][0]; S1 += red[ww][1]; S2 += red[ww][2]; S3 += red[ww][3];
    }
    const double sc = S0 / S1;
    const double r = (sc * sc * S1 - 2.0 * sc * S2 + S3) /
                     ((double)N_PTS * (double)N_PTS - (double)N_PTS);
    out[0] = (float)r;
  }
}

extern "C" void kernel_launch(void* const* d_in, const int* in_sizes, int n_in,
                              void* d_out, int out_size, void* d_ws, size_t ws_size,
                              hipStream_t stream) {
  const float* mapping = (const float*)d_in[0];
  const float* Dm = (const float*)d_in[1];
  float* out = (float*)d_out;
  // ws layout: nrm 16KB | part 128KB | Mhi 512KB | Mlo 512KB  (~1.2 MB)
  float* nrm = (float*)d_ws;
  double* part = (double*)((char*)d_ws + 16384);
  ushort* Mhi = (ushort*)((char*)d_ws + 16384 + 131072);
  ushort* Mlo = (ushort*)((char*)d_ws + 16384 + 131072 + 524288);

  prep_kernel<<<dim3(N_PTS), dim3(64), 0, stream>>>(mapping, Mhi, Mlo, nrm);
  distortion_main<<<dim3(N_PTS / TILE, N_PTS / TILE), dim3(256), 0, stream>>>(
      Mhi, Mlo, Dm, nrm, part);
  distortion_final<<<1, 1024, 0, stream>>>(part, out);
}

// Round 8
// 41.511 us; speedup vs baseline: 1.5701x; 1.5701x over previous
//
#include <hip/hip_runtime.h>
#include <hip/hip_bf16.h>

#define N_PTS 4096
#define D_EMB 64
#define TILE  128
#define NWAVE ((N_PTS / TILE) * (N_PTS / TILE) * 4)   // 4096 waves in main grid

typedef __attribute__((ext_vector_type(8))) short bf16x8;  // 8 bf16 = 4 VGPR
typedef __attribute__((ext_vector_type(4))) float f32x4;   // MFMA 16x16 acc

// ---------------------------------------------------------------------------
// Fused prep: bf16 hi/lo split + exact f32 row squared-norms.
// ---------------------------------------------------------------------------
__global__ void prep_kernel(const float* __restrict__ mapping,
                            ushort* __restrict__ Mhi,
                            ushort* __restrict__ Mlo,
                            float* __restrict__ nrm) {
  const int row = blockIdx.x;
  const int l = threadIdx.x;          // 0..63
  const int idx = row * D_EMB + l;
  const float x = mapping[idx];
  __hip_bfloat16 h = __float2bfloat16(x);
  const float hf = __bfloat162float(h);
  __hip_bfloat16 lo = __float2bfloat16(x - hf);
  Mhi[idx] = *reinterpret_cast<ushort*>(&h);
  Mlo[idx] = *reinterpret_cast<ushort*>(&lo);
  float s = x * x;
  #pragma unroll
  for (int off = 32; off > 0; off >>= 1) s += __shfl_down(s, off);
  if (l == 0) nrm[row] = s;
}

// ---------------------------------------------------------------------------
// MFMA gram (operand-SWAPPED) + fused distortion partial sums.
// dot = Hj.Hi + Hj.Li + Lj.Hi  (Li.Lj dropped; absmax 0.0 in R6/R7).
//
// Operand swap: acc[m][n] = mfma(fragJ, fragI) -> transposed tile, so a
// lane holds 4 CONSECUTIVE D-columns:
//   out row (j): gj = j0 + n*16 + kg*4 + reg   (reg 0..3 consecutive)
//   out col (i): gi = i0 + m*16 + r16
// => epilogue D access is one float4 per (m,n) per lane (16 float4 total)
// instead of R6/R7's 64 scalars; nrm[j] is float4 too. Same bytes, 4x
// fewer latency slots.
//
// R7 lesson: do NOT phase fragment loads to save VGPRs — serialized
// load->mfma chains (MfmaUtil 3%, 78us). Up-front loads (R6 structure)
// give the compiler 16 independent loads to hoist over 48 MFMAs.
// R5 lesson: contention-free per-wave partial writes (NO atomics).
// R2/R3 lesson: no min-waves launch_bounds arg (forced spills).
// ---------------------------------------------------------------------------
__global__ __launch_bounds__(256) void distortion_main(
    const ushort* __restrict__ Mhi, const ushort* __restrict__ Mlo,
    const float* __restrict__ Dm, const float* __restrict__ nrm,
    double* __restrict__ part) {
  const int t = threadIdx.x;
  const int w = t >> 6, l = t & 63;
  const int r16 = l & 15;        // fragment row/col within 16
  const int kg = l >> 4;         // k-group 0..3
  const int wr = w >> 1, wc = w & 1;
  const int i0 = blockIdx.y * TILE + wr * 64;   // wave i-panel base
  const int j0 = blockIdx.x * TILE + wc * 64;   // wave j-panel base

  f32x4 acc[4][4] = {};  // acc[m][n]: cols gi = i0+m*16+r16, rows gj = j0+n*16+kg*4+reg

  #pragma unroll
  for (int ks = 0; ks < 2; ++ks) {
    const int koff = ks * 32 + kg * 8;
    bf16x8 aH[4], aL[4], bH[4], bL[4];   // a = i-panel, b = j-panel
    #pragma unroll
    for (int m = 0; m < 4; ++m) {
      const size_t off = (size_t)(i0 + m * 16 + r16) * D_EMB + koff;
      aH[m] = *(const bf16x8*)(Mhi + off);
      aL[m] = *(const bf16x8*)(Mlo + off);
    }
    #pragma unroll
    for (int n = 0; n < 4; ++n) {
      const size_t off = (size_t)(j0 + n * 16 + r16) * D_EMB + koff;
      bH[n] = *(const bf16x8*)(Mhi + off);
      bL[n] = *(const bf16x8*)(Mlo + off);
    }
    #pragma unroll
    for (int m = 0; m < 4; ++m)
      #pragma unroll
      for (int n = 0; n < 4; ++n) {
        acc[m][n] = __builtin_amdgcn_mfma_f32_16x16x32_bf16(
            bH[n], aH[m], acc[m][n], 0, 0, 0);   // Hj.Hi
        acc[m][n] = __builtin_amdgcn_mfma_f32_16x16x32_bf16(
            bH[n], aL[m], acc[m][n], 0, 0, 0);   // Hj.Li
        acc[m][n] = __builtin_amdgcn_mfma_f32_16x16x32_bf16(
            bL[n], aH[m], acc[m][n], 0, 0, 0);   // Lj.Hi
      }
  }

  // ---- epilogue: distances + distortion partial sums, float4 D/nrm loads
  float rA[4];
  #pragma unroll
  for (int m = 0; m < 4; ++m) rA[m] = nrm[i0 + m * 16 + r16];

  float s1 = 0.f, s2 = 0.f, s3 = 0.f, s4 = 0.f;
  #pragma unroll
  for (int m = 0; m < 4; ++m) {
    const int gi = i0 + m * 16 + r16;            // D row for this lane/m
    const float* __restrict__ Drow = Dm + (size_t)gi * N_PTS;
    #pragma unroll
    for (int n = 0; n < 4; ++n) {
      const int gj0 = j0 + n * 16 + kg * 4;      // first of 4 consecutive cols
      const float4 Dv4 = *(const float4*)(Drow + gj0);
      const float4 rB4 = *(const float4*)(nrm + gj0);
      #pragma unroll
      for (int r = 0; r < 4; ++r) {
        const float Dv = (r == 0) ? Dv4.x : (r == 1) ? Dv4.y : (r == 2) ? Dv4.z : Dv4.w;
        const float rB = (r == 0) ? rB4.x : (r == 1) ? rB4.y : (r == 2) ? rB4.z : rB4.w;
        const float dot = acc[m][n][r];
        const float sq = fmaxf(rA[m] + rB - 2.f * dot, 0.f);
        float dd = __builtin_amdgcn_sqrtf(sq);
        const bool diag = (gi == gj0 + r);
        if (diag) dd = 0.f;                      // exact: ||x-x|| = 0
        const float denom = Dv + (diag ? 1.f : 0.f) + 1e-8f;
        const float rd = __builtin_amdgcn_rcpf(denom);
        const float av = dd * rd;                // a = d/denom
        const float bv = Dv * rd;                // b = D/denom
        s1 += av;
        s2 = fmaf(av, av, s2);
        s3 = fmaf(av, bv, s3);
        s4 = fmaf(bv, bv, s4);
      }
    }
  }

  // ---- wave shuffle reduce, one contention-free f64 write per wave
  #pragma unroll
  for (int off = 32; off > 0; off >>= 1) {
    s1 += __shfl_down(s1, off);
    s2 += __shfl_down(s2, off);
    s3 += __shfl_down(s3, off);
    s4 += __shfl_down(s4, off);
  }
  if (l == 0) {
    const int gw = ((blockIdx.y * gridDim.x + blockIdx.x) << 2) + w;
    part[0 * NWAVE + gw] = (double)s1;
    part[1 * NWAVE + gw] = (double)s2;
    part[2 * NWAVE + gw] = (double)s3;
    part[3 * NWAVE + gw] = (double)s4;
  }
}

// ---------------------------------------------------------------------------
// Reduce 4 x NWAVE partials; emit sum(dist) = s^2*S2 - 2 s S3 + S4, s=S1/S2.
// ---------------------------------------------------------------------------
__global__ __launch_bounds__(1024) void distortion_final(
    const double* __restrict__ part, float* __restrict__ out) {
  __shared__ double red[16][4];
  const int t = threadIdx.x;
  double s[4];
  #pragma unroll
  for (int k = 0; k < 4; ++k) {
    double v = 0.0;
    #pragma unroll
    for (int c = 0; c < NWAVE / 1024; ++c) v += part[k * NWAVE + c * 1024 + t];
    s[k] = v;
  }
  #pragma unroll
  for (int off = 32; off > 0; off >>= 1)
    #pragma unroll
    for (int k = 0; k < 4; ++k) s[k] += __shfl_down(s[k], off);
  const int w = t >> 6, l = t & 63;
  if (l == 0) {
    #pragma unroll
    for (int k = 0; k < 4; ++k) red[w][k] = s[k];
  }
  __syncthreads();
  if (t == 0) {
    double S0 = 0, S1 = 0, S2 = 0, S3 = 0;
    #pragma unroll
    for (int ww = 0; ww < 16; ++ww) {
      S0 += red[ww][0]; S1 += red[ww][1]; S2 += red[ww][2]; S3 += red[ww][3];
    }
    const double sc = S0 / S1;
    const double r = (sc * sc * S1 - 2.0 * sc * S2 + S3) /
                     ((double)N_PTS * (double)N_PTS - (double)N_PTS);
    out[0] = (float)r;
  }
}

extern "C" void kernel_launch(void* const* d_in, const int* in_sizes, int n_in,
                              void* d_out, int out_size, void* d_ws, size_t ws_size,
                              hipStream_t stream) {
  const float* mapping = (const float*)d_in[0];
  const float* Dm = (const float*)d_in[1];
  float* out = (float*)d_out;
  // ws layout: nrm 16KB | part 128KB | Mhi 512KB | Mlo 512KB  (~1.2 MB)
  float* nrm = (float*)d_ws;
  double* part = (double*)((char*)d_ws + 16384);
  ushort* Mhi = (ushort*)((char*)d_ws + 16384 + 131072);
  ushort* Mlo = (ushort*)((char*)d_ws + 16384 + 131072 + 524288);

  prep_kernel<<<dim3(N_PTS), dim3(64), 0, stream>>>(mapping, Mhi, Mlo, nrm);
  distortion_main<<<dim3(N_PTS / TILE, N_PTS / TILE), dim3(256), 0, stream>>>(
      Mhi, Mlo, Dm, nrm, part);
  distortion_final<<<1, 1024, 0, stream>>>(part, out);
}